// Round 10
// baseline (33.679 us; speedup 1.0000x reference)
//
#include <hip/hip_runtime.h>

#define NCELLS (16384 * 7 * 7)   // 802816
#define NPAIR (NCELLS / 2)       // 401408
#define NBLK (NPAIR / 256)       // 1568 blocks, 2 cells/thread
#define NPART (NBLK * 4)         // one partial per wave = 6272
#define INV_BATCH (1.0f / 16384.0f)
#define EPS 1e-12f
#define IMG 448.0f
#define CELL (448.0f / 7.0f)     // 64
#define L_COORD 5.0f
#define L_NOOBJ 0.5f

__device__ __forceinline__ float iou_f(const float* bp, const float* bt) {
    float cxp = bp[0] * CELL, cyp = bp[1] * CELL;
    float wp  = bp[2] * IMG,  hp  = bp[3] * IMG;
    float cxt = bt[0] * CELL, cyt = bt[1] * CELL;
    float wt  = bt[2] * IMG,  ht  = bt[3] * IMG;
    float iw = fmaxf(fminf(cxp + wp * 0.5f, cxt + wt * 0.5f) -
                     fmaxf(cxp - wp * 0.5f, cxt - wt * 0.5f), 0.0f);
    float ih = fmaxf(fminf(cyp + hp * 0.5f, cyt + ht * 0.5f) -
                     fmaxf(cyp - hp * 0.5f, cyt - ht * 0.5f), 0.0f);
    float inter = iw * ih;
    float uni = wp * hp + wt * ht - inter;
    return inter / (uni + EPS);
}

__device__ __forceinline__ float coord_loss(const float* bp, const float* tb) {
    float xy = (bp[0] - tb[0]) * (bp[0] - tb[0]) + (bp[1] - tb[1]) * (bp[1] - tb[1]);
    float s2 = sqrtf(bp[2] + EPS) - sqrtf(tb[2] + EPS);
    float s3 = sqrtf(bp[3] + EPS) - sqrtf(tb[3] + EPS);
    return xy + s2 * s2 + s3 * s3;
}

__device__ __forceinline__ float one_cell(const float* pv, const float* tv) {
    float c1 = pv[4], c2 = pv[9];
    if (tv[0] != 0.0f) {
        const float* tbx = tv + 1;
        float iou1 = iou_f(pv + 0, tbx);
        float iou2 = iou_f(pv + 5, tbx);
        float cl1 = coord_loss(pv + 0, tbx);
        float cl2 = coord_loss(pv + 5, tbx);
        int c = (int)tv[0] - 1;
        float cls = 0.0f;
        #pragma unroll
        for (int k = 0; k < 20; ++k) {
            float d = pv[10 + k] - (k == c ? 1.0f : 0.0f);
            cls += d * d;
        }
        float d1 = c1 - iou1, d2 = c2 - iou2;
        return d1 * d1 + d2 * d2 + L_COORD * (cl1 + cl2) + cls;
    } else {
        return L_NOOBJ * (c1 * c1 + c2 * c2);
    }
}

// Kernel 1: 2 cells/thread -> y_pre slice = 60 floats = 240 B, 16B-aligned:
// 15x float4 loads (vs 30x float2). y_true: 4x float4. Per-wave partial store.
__global__ void __launch_bounds__(256) yolo_partial_kernel(
        const float* __restrict__ y_pre,
        const float* __restrict__ y_true,
        float* __restrict__ partial) {
    const int tid = threadIdx.x;
    const int pair = blockIdx.x * 256 + tid;

    // ---- y_pre: 60 floats via 15 aligned float4 ----
    float pv[60];
    {
        const float4* p4 = reinterpret_cast<const float4*>(y_pre + (size_t)pair * 60);
        #pragma unroll
        for (int i = 0; i < 15; ++i) {
            float4 v = p4[i];
            pv[4 * i]     = v.x;
            pv[4 * i + 1] = v.y;
            pv[4 * i + 2] = v.z;
            pv[4 * i + 3] = v.w;
        }
    }
    // ---- y_true: 16 floats via 4 aligned float4 ----
    float tv[16];
    {
        const float4* t4 = reinterpret_cast<const float4*>(y_true) + (size_t)pair * 4;
        #pragma unroll
        for (int i = 0; i < 4; ++i) {
            float4 v = t4[i];
            tv[4 * i]     = v.x;
            tv[4 * i + 1] = v.y;
            tv[4 * i + 2] = v.z;
            tv[4 * i + 3] = v.w;
        }
    }

    float local = (one_cell(pv, tv) + one_cell(pv + 30, tv + 8)) * INV_BATCH;

    #pragma unroll
    for (int off = 32; off > 0; off >>= 1)
        local += __shfl_down(local, off);

    if ((tid & 63) == 0)
        partial[blockIdx.x * 4 + (tid >> 6)] = local;   // per-wave, no barrier
}

// Kernel 2: one block sums 6272 partials (float4 loads), writes out[0].
__global__ void __launch_bounds__(256) yolo_final_kernel(
        const float* __restrict__ partial,
        float* __restrict__ out) {
    const int tid = threadIdx.x;
    const float4* p4 = reinterpret_cast<const float4*>(partial);
    float local = 0.0f;
    #pragma unroll 4
    for (int i = tid; i < NPART / 4; i += 256) {        // 1568 float4 -> 7 iters
        float4 v = p4[i];
        local += (v.x + v.y) + (v.z + v.w);
    }
    #pragma unroll
    for (int off = 32; off > 0; off >>= 1)
        local += __shfl_down(local, off);

    __shared__ float wsum[4];
    if ((tid & 63) == 0) wsum[tid >> 6] = local;
    __syncthreads();
    if (tid == 0)
        out[0] = wsum[0] + wsum[1] + wsum[2] + wsum[3];
}

extern "C" void kernel_launch(void* const* d_in, const int* in_sizes, int n_in,
                              void* d_out, int out_size, void* d_ws, size_t ws_size,
                              hipStream_t stream) {
    const float* y_pre  = (const float*)d_in[0];
    const float* y_true = (const float*)d_in[1];
    float* out = (float*)d_out;
    float* partial = (float*)d_ws;   // 6272 floats = 24.5 KB

    yolo_partial_kernel<<<NBLK, 256, 0, stream>>>(y_pre, y_true, partial);
    yolo_final_kernel<<<1, 256, 0, stream>>>(partial, out);
}

// Round 11
// 27.223 us; speedup vs baseline: 1.2371x; 1.2371x over previous
//
#include <hip/hip_runtime.h>

#define NCELLS (16384 * 7 * 7)   // 802816
#define NBLK (NCELLS / 256)      // 3136 blocks, 1 cell/thread
#define NPART (NBLK * 4)         // one partial per wave = 12544
#define INV_BATCH (1.0f / 16384.0f)
#define EPS 1e-12f
#define IMG 448.0f
#define CELL (448.0f / 7.0f)     // 64
#define L_COORD 5.0f
#define L_NOOBJ 0.5f

__device__ __forceinline__ float iou_f(const float* bp, const float* bt) {
    float cxp = bp[0] * CELL, cyp = bp[1] * CELL;
    float wp  = bp[2] * IMG,  hp  = bp[3] * IMG;
    float cxt = bt[0] * CELL, cyt = bt[1] * CELL;
    float wt  = bt[2] * IMG,  ht  = bt[3] * IMG;
    float iw = fmaxf(fminf(cxp + wp * 0.5f, cxt + wt * 0.5f) -
                     fmaxf(cxp - wp * 0.5f, cxt - wt * 0.5f), 0.0f);
    float ih = fmaxf(fminf(cyp + hp * 0.5f, cyt + ht * 0.5f) -
                     fmaxf(cyp - hp * 0.5f, cyt - ht * 0.5f), 0.0f);
    float inter = iw * ih;
    float uni = wp * hp + wt * ht - inter;
    return inter / (uni + EPS);
}

__device__ __forceinline__ float coord_loss(const float* bp, const float* tb) {
    float xy = (bp[0] - tb[0]) * (bp[0] - tb[0]) + (bp[1] - tb[1]) * (bp[1] - tb[1]);
    float s2 = sqrtf(bp[2] + EPS) - sqrtf(tb[2] + EPS);
    float s3 = sqrtf(bp[3] + EPS) - sqrtf(tb[3] + EPS);
    return xy + s2 * s2 + s3 * s3;
}

// Kernel 1: wave-private LDS staging, NO __syncthreads.
// Each wave stages its own 64 cells (480 float4, coalesced -> ~96 line
// transactions/wave vs ~930 for direct 120B-stride loads), then reads its
// own region (same-wave RAW: compiler lgkmcnt only). Grid/TLP identical to R9.
__global__ void __launch_bounds__(256) yolo_partial_kernel(
        const float* __restrict__ y_pre,
        const float* __restrict__ y_true,
        float* __restrict__ partial) {
    __shared__ float4 sp4[1920];             // 4 waves * 480 float4 = 30720 B
    const int tid  = threadIdx.x;
    const int lane = tid & 63;
    const int w    = tid >> 6;

    const float4* g4 = reinterpret_cast<const float4*>(y_pre)
                     + (size_t)blockIdx.x * 1920 + w * 480;
    float4* l4 = sp4 + w * 480;

    // ---- stage in two batches of named float4 (no indexed array -> no scratch) ----
    {
        float4 a = g4[lane];
        float4 b = g4[lane + 64];
        float4 c = g4[lane + 128];
        float4 d = g4[lane + 192];
        l4[lane]       = a;
        l4[lane + 64]  = b;
        l4[lane + 128] = c;
        l4[lane + 192] = d;
    }
    {
        float4 a = g4[lane + 256];
        float4 b = g4[lane + 320];
        float4 c = g4[lane + 384];
        l4[lane + 256] = a;
        l4[lane + 320] = b;
        l4[lane + 384] = c;
        if (lane < 32) {                     // 480 - 448 = 32 remaining
            float4 d = g4[lane + 448];
            l4[lane + 448] = d;
        }
    }

    // ---- y_true: 8 floats direct (32B/cell, line-dense) ----
    const int cell = blockIdx.x * 256 + tid;
    float tv[8];
    {
        const float4* t4 = reinterpret_cast<const float4*>(y_true) + (size_t)cell * 2;
        float4 ta = t4[0], tb4 = t4[1];
        tv[0] = ta.x; tv[1] = ta.y; tv[2] = ta.z; tv[3] = ta.w;
        tv[4] = tb4.x; tv[5] = tb4.y; tv[6] = tb4.z; tv[7] = tb4.w;
    }

    // ---- own 30 floats from own wave's LDS region (no barrier) ----
    float pv[30];
    {
        const float2* l2 = reinterpret_cast<const float2*>(
            reinterpret_cast<const float*>(sp4) + w * 1920 + lane * 30);
        #pragma unroll
        for (int i = 0; i < 15; ++i) {
            float2 v = l2[i];
            pv[2 * i]     = v.x;
            pv[2 * i + 1] = v.y;
        }
    }

    float c1 = pv[4], c2 = pv[9];
    float loss;
    if (tv[0] != 0.0f) {
        const float* tbx = tv + 1;
        float iou1 = iou_f(pv + 0, tbx);
        float iou2 = iou_f(pv + 5, tbx);
        float cl1 = coord_loss(pv + 0, tbx);
        float cl2 = coord_loss(pv + 5, tbx);
        int c = (int)tv[0] - 1;
        float cls = 0.0f;
        #pragma unroll
        for (int k = 0; k < 20; ++k) {
            float d = pv[10 + k] - (k == c ? 1.0f : 0.0f);
            cls += d * d;
        }
        float d1 = c1 - iou1, d2 = c2 - iou2;
        loss = d1 * d1 + d2 * d2 + L_COORD * (cl1 + cl2) + cls;
    } else {
        loss = L_NOOBJ * (c1 * c1 + c2 * c2);
    }
    float local = loss * INV_BATCH;

    // wave-64 reduce -> one partial per wave, no barrier, no block reduce
    #pragma unroll
    for (int off = 32; off > 0; off >>= 1)
        local += __shfl_down(local, off);

    if (lane == 0)
        partial[blockIdx.x * 4 + w] = local;
}

// Kernel 2: one block sums 12544 partials (float4 loads), writes out[0].
__global__ void __launch_bounds__(256) yolo_final_kernel(
        const float* __restrict__ partial,
        float* __restrict__ out) {
    const int tid = threadIdx.x;
    const float4* p4 = reinterpret_cast<const float4*>(partial);
    float local = 0.0f;
    #pragma unroll 4
    for (int i = tid; i < NPART / 4; i += 256) {
        float4 v = p4[i];
        local += (v.x + v.y) + (v.z + v.w);
    }
    #pragma unroll
    for (int off = 32; off > 0; off >>= 1)
        local += __shfl_down(local, off);

    __shared__ float wsum[4];
    if ((tid & 63) == 0) wsum[tid >> 6] = local;
    __syncthreads();
    if (tid == 0)
        out[0] = wsum[0] + wsum[1] + wsum[2] + wsum[3];
}

extern "C" void kernel_launch(void* const* d_in, const int* in_sizes, int n_in,
                              void* d_out, int out_size, void* d_ws, size_t ws_size,
                              hipStream_t stream) {
    const float* y_pre  = (const float*)d_in[0];
    const float* y_true = (const float*)d_in[1];
    float* out = (float*)d_out;
    float* partial = (float*)d_ws;   // 12544 floats = 49 KB

    yolo_partial_kernel<<<NBLK, 256, 0, stream>>>(y_pre, y_true, partial);
    yolo_final_kernel<<<1, 256, 0, stream>>>(partial, out);
}

// Round 12
// 25.892 us; speedup vs baseline: 1.3007x; 1.0514x over previous
//
#include <hip/hip_runtime.h>

#define NCELLS (16384 * 7 * 7)   // 802816
#define NBLK (NCELLS / 256)      // 3136 blocks, 1 cell/thread
#define NPART (NBLK * 4)         // one partial per wave = 12544
#define INV_BATCH (1.0f / 16384.0f)
#define EPS 1e-12f
#define IMG 448.0f
#define CELL (448.0f / 7.0f)     // 64
#define L_COORD 5.0f
#define L_NOOBJ 0.5f

__device__ __forceinline__ float iou_f(const float* bp, const float* bt) {
    float cxp = bp[0] * CELL, cyp = bp[1] * CELL;
    float wp  = bp[2] * IMG,  hp  = bp[3] * IMG;
    float cxt = bt[0] * CELL, cyt = bt[1] * CELL;
    float wt  = bt[2] * IMG,  ht  = bt[3] * IMG;
    float iw = fmaxf(fminf(cxp + wp * 0.5f, cxt + wt * 0.5f) -
                     fmaxf(cxp - wp * 0.5f, cxt - wt * 0.5f), 0.0f);
    float ih = fmaxf(fminf(cyp + hp * 0.5f, cyt + ht * 0.5f) -
                     fmaxf(cyp - hp * 0.5f, cyt - ht * 0.5f), 0.0f);
    float inter = iw * ih;
    float uni = wp * hp + wt * ht - inter;
    return inter / (uni + EPS);
}

__device__ __forceinline__ float coord_loss(const float* bp, const float* tb) {
    float xy = (bp[0] - tb[0]) * (bp[0] - tb[0]) + (bp[1] - tb[1]) * (bp[1] - tb[1]);
    float s2 = sqrtf(bp[2] + EPS) - sqrtf(tb[2] + EPS);
    float s3 = sqrtf(bp[3] + EPS) - sqrtf(tb[3] + EPS);
    return xy + s2 * s2 + s3 * s3;
}

// Kernel 1: wave-private async staging via global_load_lds (linear dest =
// wave-uniform base + lane*16, exactly the HW layout). No __syncthreads;
// explicit vmcnt(0) before LDS reads (same-wave dependency only).
__global__ void __launch_bounds__(256) yolo_partial_kernel(
        const float* __restrict__ y_pre,
        const float* __restrict__ y_true,
        float* __restrict__ partial) {
    __shared__ float4 sp4[1920];             // 4 waves * 480 float4 = 30720 B
    const int tid  = threadIdx.x;
    const int lane = tid & 63;
    const int w    = tid >> 6;

    const float4* g4 = reinterpret_cast<const float4*>(y_pre)
                     + (size_t)blockIdx.x * 1920 + w * 480;
    float4* l4 = sp4 + w * 480;

    // ---- async DMA: 7 full-wave batches + 1 half-wave batch = 480 float4 ----
    #pragma unroll
    for (int b = 0; b < 7; ++b) {
        __builtin_amdgcn_global_load_lds(
            (const __attribute__((address_space(1))) void*)(g4 + b * 64 + lane),
            (__attribute__((address_space(3))) void*)(l4 + b * 64),
            16, 0, 0);
    }
    if (lane < 32) {
        __builtin_amdgcn_global_load_lds(
            (const __attribute__((address_space(1))) void*)(g4 + 448 + lane),
            (__attribute__((address_space(3))) void*)(l4 + 448),
            16, 0, 0);
    }

    // ---- y_true: 8 floats direct (32B/cell, line-dense) ----
    const int cell = blockIdx.x * 256 + tid;
    float tv[8];
    {
        const float4* t4 = reinterpret_cast<const float4*>(y_true) + (size_t)cell * 2;
        float4 ta = t4[0], tb4 = t4[1];
        tv[0] = ta.x; tv[1] = ta.y; tv[2] = ta.z; tv[3] = ta.w;
        tv[4] = tb4.x; tv[5] = tb4.y; tv[6] = tb4.z; tv[7] = tb4.w;
    }

    // wait for the DMA into our wave's LDS region (and the tv loads)
    asm volatile("s_waitcnt vmcnt(0)" ::: "memory");

    // ---- own 30 floats from own wave's LDS region (no barrier) ----
    float pv[30];
    {
        const float2* l2 = reinterpret_cast<const float2*>(
            reinterpret_cast<const float*>(sp4) + w * 1920 + lane * 30);
        #pragma unroll
        for (int i = 0; i < 15; ++i) {
            float2 v = l2[i];
            pv[2 * i]     = v.x;
            pv[2 * i + 1] = v.y;
        }
    }

    float c1 = pv[4], c2 = pv[9];
    float loss;
    if (tv[0] != 0.0f) {
        const float* tbx = tv + 1;
        float iou1 = iou_f(pv + 0, tbx);
        float iou2 = iou_f(pv + 5, tbx);
        float cl1 = coord_loss(pv + 0, tbx);
        float cl2 = coord_loss(pv + 5, tbx);
        int c = (int)tv[0] - 1;
        float cls = 0.0f;
        #pragma unroll
        for (int k = 0; k < 20; ++k) {
            float d = pv[10 + k] - (k == c ? 1.0f : 0.0f);
            cls += d * d;
        }
        float d1 = c1 - iou1, d2 = c2 - iou2;
        loss = d1 * d1 + d2 * d2 + L_COORD * (cl1 + cl2) + cls;
    } else {
        loss = L_NOOBJ * (c1 * c1 + c2 * c2);
    }
    float local = loss * INV_BATCH;

    // wave-64 reduce -> one partial per wave
    #pragma unroll
    for (int off = 32; off > 0; off >>= 1)
        local += __shfl_down(local, off);

    if (lane == 0)
        partial[blockIdx.x * 4 + w] = local;
}

// Kernel 2: 1024 threads (16 waves) sum 12544 partials -> out[0].
__global__ void __launch_bounds__(1024) yolo_final_kernel(
        const float* __restrict__ partial,
        float* __restrict__ out) {
    const int tid = threadIdx.x;
    const float4* p4 = reinterpret_cast<const float4*>(partial);
    float local = 0.0f;
    #pragma unroll 4
    for (int i = tid; i < NPART / 4; i += 1024) {    // 3136 float4 -> 4 iters
        float4 v = p4[i];
        local += (v.x + v.y) + (v.z + v.w);
    }
    #pragma unroll
    for (int off = 32; off > 0; off >>= 1)
        local += __shfl_down(local, off);

    __shared__ float wsum[16];
    if ((tid & 63) == 0) wsum[tid >> 6] = local;
    __syncthreads();
    if (tid == 0) {
        float s = 0.0f;
        #pragma unroll
        for (int i = 0; i < 16; ++i) s += wsum[i];
        out[0] = s;
    }
}

extern "C" void kernel_launch(void* const* d_in, const int* in_sizes, int n_in,
                              void* d_out, int out_size, void* d_ws, size_t ws_size,
                              hipStream_t stream) {
    const float* y_pre  = (const float*)d_in[0];
    const float* y_true = (const float*)d_in[1];
    float* out = (float*)d_out;
    float* partial = (float*)d_ws;   // 12544 floats = 49 KB

    yolo_partial_kernel<<<NBLK, 256, 0, stream>>>(y_pre, y_true, partial);
    yolo_final_kernel<<<1, 1024, 0, stream>>>(partial, out);
}